// Round 11
// baseline (429.335 us; speedup 1.0000x reference)
//
#include <hip/hip_runtime.h>
#include <math.h>

#define K_CODES 1024
#define D_DIM   256
#define HW      1024          // 32*32
#define N_ROWS  32768
#define TAU     1.2e-4f       // ambiguity margin (quantized-score domain)

typedef __attribute__((ext_vector_type(8))) short bf16x8;
typedef __attribute__((ext_vector_type(4))) float f32x4;
#define MFMA16(a, b, c) __builtin_amdgcn_mfma_f32_16x16x32_bf16(a, b, c, 0, 0, 0)

__device__ __forceinline__ unsigned bf16_rne_bits(float x) {
    unsigned u = __float_as_uint(x);
    return (u + 0x7FFFu + ((u >> 16) & 1u)) >> 16;
}

// ---------- numpy-faithful pairwise sum of squares (validated round 2) ----------
__device__ __forceinline__ float pw_block128_sq(const float* a) {
    #pragma clang fp contract(off)
    float S[16];
    #pragma unroll
    for (int l = 0; l < 16; ++l) {
        float x0 = a[l],      x4 = a[64 + l];
        float x1 = a[16 + l], x5 = a[80 + l];
        float x2 = a[32 + l], x6 = a[96 + l];
        float x3 = a[48 + l], x7 = a[112 + l];
        float r0 = x0 * x0 + x4 * x4;
        float r1 = x1 * x1 + x5 * x5;
        float r2 = x2 * x2 + x6 * x6;
        float r3 = x3 * x3 + x7 * x7;
        S[l] = (r0 + r1) + (r2 + r3);
    }
    float u0 = S[0] + S[8],  u1 = S[1] + S[9],  u2 = S[2] + S[10], u3 = S[3] + S[11];
    float u4 = S[4] + S[12], u5 = S[5] + S[13], u6 = S[6] + S[14], u7 = S[7] + S[15];
    float v0 = u0 + u4, v1 = u1 + u5, v2 = u2 + u6, v3 = u3 + u7;
    return (v0 + v2) + (v1 + v3);
}
__device__ __forceinline__ float pw_sum256_sq(const float* a) {
    #pragma clang fp contract(off)
    float b0 = pw_block128_sq(a);
    float b1 = pw_block128_sq(a + 128);
    return b0 + b1;
}

// ---------------- K0: emb -> bf16 hi/lo split ----------------
__global__ void k_emb_cvt(const float* __restrict__ emb,
                          ushort* __restrict__ hi, ushort* __restrict__ lo) {
    int i = blockIdx.x * 256 + threadIdx.x;   // 65536 float4 groups
    float4 v = reinterpret_cast<const float4*>(emb)[i];
    ushort4 h, l;
    float x[4] = {v.x, v.y, v.z, v.w};
    ushort hb[4], lb[4];
    #pragma unroll
    for (int j = 0; j < 4; ++j) {
        unsigned hbits = bf16_rne_bits(x[j]);
        float hf = __uint_as_float(hbits << 16);
        unsigned lbits = bf16_rne_bits(x[j] - hf);
        hb[j] = (ushort)hbits; lb[j] = (ushort)lbits;
    }
    h.x = hb[0]; h.y = hb[1]; h.z = hb[2]; h.w = hb[3];
    l.x = lb[0]; l.y = lb[1]; l.z = lb[2]; l.w = lb[3];
    reinterpret_cast<ushort4*>(hi)[i] = h;
    reinterpret_cast<ushort4*>(lo)[i] = l;
}

// ---------------- K1: emb row norms (numpy-faithful) ----------------
__global__ void k_emb_norm(const float* __restrict__ emb, float* __restrict__ enorm) {
    int k = blockIdx.x * 256 + threadIdx.x;
    if (k < K_CODES) enorm[k] = pw_sum256_sq(emb + (size_t)k * D_DIM);
}

// ---------------- K2: MFMA screen ----------------
#define BT_STR 264              // padded ushort stride (16B-aligned rows)
#define BT_BLK (16 * BT_STR)    // one 16-code half-tile (hi or lo)
__global__ __launch_bounds__(256, 2) void k_screen_mfma(
    const float* __restrict__ z,
    const ushort* __restrict__ emb_hi, const ushort* __restrict__ emb_lo,
    const float* __restrict__ enorm, float* __restrict__ zn_row,
    int* __restrict__ idx_ws, int* __restrict__ worklist, int* __restrict__ nflag)
{
    __shared__ __align__(16) float zl[64 * 257];   // 65792 B; reused as B tiles
    __shared__ float enorm_lds[K_CODES];
    __shared__ float zn_sh[64];

    const int tid  = threadIdx.x;
    const int lane = tid & 63, wave = tid >> 6;
    const int blk  = blockIdx.x;                   // 512 blocks
    const int batch = blk >> 4;
    const int p0    = (blk & 15) * 64;
    const float* zb = z + (size_t)batch * D_DIM * HW;

    // stage z tile (f32): zl[p*257 + d] = z[batch][d][p0+p]
    {
        int p = tid & 63;
        for (int d = tid >> 6; d < D_DIM; d += 4)
            zl[p * 257 + d] = zb[(size_t)d * HW + p0 + p];
    }
    // stage enorm
    for (int i = tid; i < K_CODES; i += 256) enorm_lds[i] = enorm[i];
    __syncthreads();

    // numpy-faithful zn per row (also persisted for the recheck kernel)
    if (tid < 64) {
        float zn = pw_sum256_sq(&zl[tid * 257]);
        zn_sh[tid] = zn;
        zn_row[blk * 64 + tid] = zn;
    }

    // build A fragments in registers (hi/lo bf16), 16 rows per wave
    const int fr = lane & 15, fg = lane >> 4;
    bf16x8 Ah[8], Al[8];
    {
        const float* zr = &zl[(wave * 16 + fr) * 257];
        #pragma unroll
        for (int s = 0; s < 8; ++s) {
            int c0 = s * 32 + fg * 8;
            bf16x8 h, l;
            #pragma unroll
            for (int j = 0; j < 8; ++j) {
                float x = zr[c0 + j];
                unsigned hb = bf16_rne_bits(x);
                float hf = __uint_as_float(hb << 16);
                unsigned lb = bf16_rne_bits(x - hf);
                h[j] = (short)hb; l[j] = (short)lb;
            }
            Ah[s] = h; Al[s] = l;
        }
    }
    __syncthreads();   // zl (f32) dead; B tiles may now overwrite it

    ushort* bt = reinterpret_cast<ushort*>(zl);    // [2 buf][hi,lo][16][BT_STR]

    auto stage = [&](int buf, int kt) {
        int row = tid >> 5, d16 = tid & 31;
        #pragma unroll
        for (int i = 0; i < 2; ++i) {
            int r = row + 8 * i;
            size_t src = ((size_t)(kt * 16 + r) << 8) + d16 * 8;
            uint4 vh = *reinterpret_cast<const uint4*>(emb_hi + src);
            uint4 vl = *reinterpret_cast<const uint4*>(emb_lo + src);
            *reinterpret_cast<uint4*>(&bt[(buf * 2 + 0) * BT_BLK + r * BT_STR + d16 * 8]) = vh;
            *reinterpret_cast<uint4*>(&bt[(buf * 2 + 1) * BT_BLK + r * BT_STR + d16 * 8]) = vl;
        }
    };

    float zn4[4];
    #pragma unroll
    for (int r = 0; r < 4; ++r) zn4[r] = zn_sh[wave * 16 + fg * 4 + r];

    float b1v[4] = {1e30f, 1e30f, 1e30f, 1e30f};
    float b2v[4] = {1e30f, 1e30f, 1e30f, 1e30f};
    int   b1i[4] = {0, 0, 0, 0};

    stage(0, 0);
    __syncthreads();

    const int boff = fr * BT_STR + fg * 8;
    for (int kt = 0; kt < 64; ++kt) {
        int cur = kt & 1;
        if (kt < 63) stage(cur ^ 1, kt + 1);

        f32x4 aHH = {0.f, 0.f, 0.f, 0.f};
        f32x4 aHM = {0.f, 0.f, 0.f, 0.f};
        f32x4 aLH = {0.f, 0.f, 0.f, 0.f};
        const ushort* bhp = bt + cur * 2 * BT_BLK + boff;
        const ushort* blp = bhp + BT_BLK;
        #pragma unroll
        for (int s = 0; s < 8; ++s) {
            bf16x8 Bh = *reinterpret_cast<const bf16x8*>(bhp + s * 32);
            bf16x8 Bl = *reinterpret_cast<const bf16x8*>(blp + s * 32);
            aHH = MFMA16(Ah[s], Bh, aHH);
            aHM = MFMA16(Ah[s], Bl, aHM);
            aLH = MFMA16(Al[s], Bh, aLH);
        }
        {
            #pragma clang fp contract(off)
            float en = enorm_lds[kt * 16 + fr];
            int kk = kt * 16 + fr;
            #pragma unroll
            for (int r = 0; r < 4; ++r) {
                float m  = aHH[r] + (aHM[r] + aLH[r]);
                float t1 = zn4[r] + en;
                float s  = t1 - 2.0f * m;
                if (s < b1v[r]) { b2v[r] = b1v[r]; b1v[r] = s; b1i[r] = kk; }
                else if (s < b2v[r]) b2v[r] = s;
            }
        }
        __syncthreads();
    }

    // merge best1/best2 across the 16 lanes of each row group
    const int n0w = blk * 64 + wave * 16;
    #pragma unroll
    for (int r = 0; r < 4; ++r) {
        float v1 = b1v[r]; int i1 = b1i[r]; float v2 = b2v[r];
        #pragma unroll
        for (int o = 8; o >= 1; o >>= 1) {
            float ov1 = __shfl_xor(v1, o);
            int   oi1 = __shfl_xor(i1, o);
            float ov2 = __shfl_xor(v2, o);
            bool take = (ov1 < v1) || (ov1 == v1 && oi1 < i1);
            float loser = take ? v1 : ov1;
            if (take) { v1 = ov1; i1 = oi1; }
            v2 = fminf(fminf(v2, ov2), loser);
        }
        if (fr == 0) {
            int n = n0w + fg * 4 + r;
            idx_ws[n] = i1;
            if (v2 - v1 <= TAU) {
                int slot = atomicAdd(nflag, 1);
                worklist[slot] = n;
            }
        }
    }
}

// ---------------- K3: epilogue (zq, loss, idxf, enc ones, counts) ----------------
__global__ __launch_bounds__(256) void k_epilogue(
    const float* __restrict__ z, const float* __restrict__ emb,
    const int* __restrict__ idx_ws,
    float* __restrict__ zq_out, float* __restrict__ idxf_out,
    float* __restrict__ enc, float* __restrict__ loss_row,
    int* __restrict__ counts)
{
    __shared__ int kb[64];
    __shared__ float lpart[4][64];
    const int tid = threadIdx.x;
    const int blk = blockIdx.x;                 // 512
    const int batch = blk >> 4;
    const int p0 = (blk & 15) * 64;
    const int n0 = blk * 64;

    if (tid < 64) {
        int k = idx_ws[n0 + tid];
        kb[tid] = k;
        idxf_out[n0 + tid] = (float)k;
        enc[(size_t)(n0 + tid) * K_CODES + k] = 1.0f;
        atomicAdd(&counts[k], 1);
    }
    __syncthreads();

    int p = tid & 63, dg = tid >> 6;
    const float* zp = z + (size_t)batch * D_DIM * HW + p0 + p;
    float* zqp = zq_out + (size_t)batch * D_DIM * HW + p0 + p;
    const float* er = emb + (size_t)kb[p] * D_DIM;
    float ls = 0.0f;
    for (int d = dg * 64; d < dg * 64 + 64; ++d) {
        float e = er[d];
        float zv = zp[(size_t)d * HW];
        float df = e - zv;
        ls += df * df;
        zqp[(size_t)d * HW] = e;
    }
    lpart[dg][p] = ls;
    __syncthreads();
    if (tid < 64)
        loss_row[n0 + tid] = (lpart[0][tid] + lpart[1][tid]) + (lpart[2][tid] + lpart[3][tid]);
}

// ---------------- K4: exact f64 recheck — one block per flagged row ----------------
// Thread t: slot = t>>2 (code lane), qt = t&3 (64-dim quarter). Pass pp:
// code c = pp*64 + slot. A wave reads 16 KB of emb CONTIGUOUSLY per pass
// (L2-resident codebook, no LDS staging, no barriers in the loop).
// 4-lane fixed shuffle tree -> deterministic f64 dot; qt==0 lanes track
// (v,k) ascending; validated first-min merge; fix fused (only if changed).
__global__ __launch_bounds__(256, 4) void k_recheck(
    const float* __restrict__ z, const float* __restrict__ emb,
    const float* __restrict__ enorm, const float* __restrict__ zn_row,
    const int* __restrict__ worklist, const int* __restrict__ nflag,
    int* __restrict__ idx_ws, int* __restrict__ counts,
    float* __restrict__ loss_row, float* __restrict__ zq_out,
    float* __restrict__ idxf_out, float* __restrict__ enc)
{
    __shared__ __align__(16) float zrow[D_DIM];
    __shared__ float wv[4]; __shared__ int wi[4];
    __shared__ int fi_sh;

    const int tid  = threadIdx.x;
    const int lane = tid & 63, wave = tid >> 6;
    const int slot = tid >> 2, qt = tid & 3;
    const int nf = *nflag;

    for (int j = blockIdx.x; j < nf; j += gridDim.x) {
        const int n = worklist[j];
        const int batch = n >> 10, p = n & (HW - 1);

        zrow[tid] = z[(size_t)batch * D_DIM * HW + (size_t)tid * HW + p];
        __syncthreads();

        float bv = 1e30f; int bi = 0;
        const float znr = zn_row[n];
        const float* zq4 = &zrow[qt * 64];

        for (int pp = 0; pp < 16; ++pp) {
            const int c = pp * 64 + slot;
            const float* er = emb + (size_t)c * D_DIM + qt * 64;
            double a0 = 0.0, a1 = 0.0, a2 = 0.0, a3 = 0.0;
            #pragma unroll
            for (int d = 0; d < 64; d += 4) {
                float4 e4 = *reinterpret_cast<const float4*>(er + d);
                float4 z4 = *reinterpret_cast<const float4*>(zq4 + d);
                a0 += (double)z4.x * (double)e4.x;
                a1 += (double)z4.y * (double)e4.y;
                a2 += (double)z4.z * (double)e4.z;
                a3 += (double)z4.w * (double)e4.w;
            }
            double part = (a0 + a1) + (a2 + a3);
            part += __shfl_xor(part, 1);   // fixed tree across qt
            part += __shfl_xor(part, 2);
            {
                #pragma clang fp contract(off)
                float mf = (float)part;
                float t1 = znr + enorm[c];
                float s  = t1 - 2.0f * mf;
                if (qt == 0) {
                    if (s < bv) { bv = s; bi = c; }   // c ascending per slot
                }
            }
        }
        if (qt != 0) bv = 1e30f;

        // wave butterfly with first-index tiebreak (validated merge rule)
        #pragma unroll
        for (int o = 32; o >= 1; o >>= 1) {
            float ov = __shfl_xor(bv, o);
            int   oi = __shfl_xor(bi, o);
            if (ov < bv || (ov == bv && oi < bi)) { bv = ov; bi = oi; }
        }
        if (lane == 0) { wv[wave] = bv; wi[wave] = bi; }
        __syncthreads();
        if (tid == 0) {
            float fv = wv[0]; int fi = wi[0];
            #pragma unroll
            for (int w = 1; w < 4; ++w)
                if (wv[w] < fv || (wv[w] == fv && wi[w] < fi)) { fv = wv[w]; fi = wi[w]; }
            fi_sh = fi;
        }
        __syncthreads();

        const int fi = fi_sh;
        const int old = idx_ws[n];
        if (fi != old) {
            // wave 0 repairs this row (z-row still in LDS)
            if (wave == 0) {
                float lsum = 0.0f;
                float* zqp = zq_out + (size_t)batch * D_DIM * HW + p;
                #pragma unroll
                for (int i = 0; i < 4; ++i) {
                    int d = lane + 64 * i;
                    float e = emb[(size_t)fi * D_DIM + d];
                    float df = e - zrow[d];
                    lsum += df * df;
                    zqp[(size_t)d * HW] = e;
                }
                #pragma unroll
                for (int o = 32; o >= 1; o >>= 1) lsum += __shfl_xor(lsum, o);
                if (lane == 0) {
                    loss_row[n] = lsum;
                    idx_ws[n] = fi;
                    idxf_out[n] = (float)fi;
                    enc[(size_t)n * K_CODES + old] = 0.0f;
                    enc[(size_t)n * K_CODES + fi] = 1.0f;
                    atomicSub(&counts[old], 1);
                    atomicAdd(&counts[fi], 1);
                }
            }
        }
        __syncthreads();   // protect zrow before next row
    }
}

// ---------------- K5: finalize loss + perplexity ----------------
__global__ void k_final(const float* __restrict__ loss_row,
                        const int* __restrict__ counts,
                        float* __restrict__ out_loss, float* __restrict__ out_perp) {
    __shared__ float la[4], pa[4];
    int tid = threadIdx.x;
    float ls = 0.0f, ps = 0.0f;
    for (int i = tid; i < N_ROWS; i += 256) ls += loss_row[i];
    for (int i = tid; i < K_CODES; i += 256) {
        float em = (float)counts[i] * (1.0f / (float)N_ROWS);
        ps += em * logf(em + 1e-10f);
    }
    #pragma unroll
    for (int off = 32; off > 0; off >>= 1) {
        ls += __shfl_down(ls, off);
        ps += __shfl_down(ps, off);
    }
    if ((tid & 63) == 0) { la[tid >> 6] = ls; pa[tid >> 6] = ps; }
    __syncthreads();
    if (tid == 0) {
        float L = (la[0] + la[1] + la[2] + la[3]) * (1.25f / (float)((size_t)N_ROWS * D_DIM));
        float P = expf(-(pa[0] + pa[1] + pa[2] + pa[3]));
        *out_loss = L;
        *out_perp = P;
    }
}

extern "C" void kernel_launch(void* const* d_in, const int* in_sizes, int n_in,
                              void* d_out, int out_size, void* d_ws, size_t ws_size,
                              hipStream_t stream) {
    const float* z   = (const float*)d_in[0];
    const float* emb = (const float*)d_in[1];
    float* out = (float*)d_out;

    // output layout (floats): loss | z_q_out | perplexity | min_encodings | idx
    float* out_loss = out;
    float* out_zq   = out + 1;
    float* out_perp = out + 1 + (size_t)N_ROWS * D_DIM;
    float* out_enc  = out_perp + 1;
    float* out_idxf = out_enc + (size_t)N_ROWS * K_CODES;

    char* ws = (char*)d_ws;
    int*    idx_ws   = (int*)(ws + 0);           // 131072 B
    int*    counts   = (int*)(ws + 131072);      // 4096 B
    float*  enorm    = (float*)(ws + 135168);    // 4096 B
    float*  loss_row = (float*)(ws + 139264);    // 131072 B
    int*    worklist = (int*)(ws + 270336);      // 131072 B
    int*    nflag    = (int*)(ws + 401408);      // 256 B
    ushort* emb_hi   = (ushort*)(ws + 401664);   // 524288 B
    ushort* emb_lo   = (ushort*)(ws + 925952);   // 524288 B
    float*  zn_row   = (float*)(ws + 1450240);   // 131072 B

    hipMemsetAsync(counts, 0, K_CODES * sizeof(int), stream);
    hipMemsetAsync(nflag, 0, sizeof(int), stream);
    hipMemsetAsync(out_enc, 0, (size_t)N_ROWS * K_CODES * sizeof(float), stream);

    k_emb_cvt<<<256, 256, 0, stream>>>(emb, emb_hi, emb_lo);
    k_emb_norm<<<(K_CODES + 255) / 256, 256, 0, stream>>>(emb, enorm);
    k_screen_mfma<<<512, 256, 0, stream>>>(z, emb_hi, emb_lo, enorm, zn_row,
                                           idx_ws, worklist, nflag);
    k_epilogue<<<512, 256, 0, stream>>>(z, emb, idx_ws, out_zq, out_idxf,
                                        out_enc, loss_row, counts);
    k_recheck<<<512, 256, 0, stream>>>(z, emb, enorm, zn_row, worklist, nflag,
                                       idx_ws, counts, loss_row, out_zq,
                                       out_idxf, out_enc);
    k_final<<<1, 256, 0, stream>>>(loss_row, counts, out_loss, out_perp);
}

// Round 12
// 326.158 us; speedup vs baseline: 1.3163x; 1.3163x over previous
//
#include <hip/hip_runtime.h>
#include <math.h>

#define K_CODES 1024
#define D_DIM   256
#define HW      1024          // 32*32
#define N_ROWS  32768
#define TAU     1.2e-4f       // ambiguity margin (quantized-score domain)

typedef __attribute__((ext_vector_type(8))) short bf16x8;
typedef __attribute__((ext_vector_type(4))) float f32x4;
#define MFMA16(a, b, c) __builtin_amdgcn_mfma_f32_16x16x32_bf16(a, b, c, 0, 0, 0)

__device__ __forceinline__ unsigned bf16_rne_bits(float x) {
    unsigned u = __float_as_uint(x);
    return (u + 0x7FFFu + ((u >> 16) & 1u)) >> 16;
}

// ---------- numpy-faithful pairwise sum of squares (validated round 2) ----------
__device__ __forceinline__ float pw_block128_sq(const float* a) {
    #pragma clang fp contract(off)
    float S[16];
    #pragma unroll
    for (int l = 0; l < 16; ++l) {
        float x0 = a[l],      x4 = a[64 + l];
        float x1 = a[16 + l], x5 = a[80 + l];
        float x2 = a[32 + l], x6 = a[96 + l];
        float x3 = a[48 + l], x7 = a[112 + l];
        float r0 = x0 * x0 + x4 * x4;
        float r1 = x1 * x1 + x5 * x5;
        float r2 = x2 * x2 + x6 * x6;
        float r3 = x3 * x3 + x7 * x7;
        S[l] = (r0 + r1) + (r2 + r3);
    }
    float u0 = S[0] + S[8],  u1 = S[1] + S[9],  u2 = S[2] + S[10], u3 = S[3] + S[11];
    float u4 = S[4] + S[12], u5 = S[5] + S[13], u6 = S[6] + S[14], u7 = S[7] + S[15];
    float v0 = u0 + u4, v1 = u1 + u5, v2 = u2 + u6, v3 = u3 + u7;
    return (v0 + v2) + (v1 + v3);
}
__device__ __forceinline__ float pw_sum256_sq(const float* a) {
    #pragma clang fp contract(off)
    float b0 = pw_block128_sq(a);
    float b1 = pw_block128_sq(a + 128);
    return b0 + b1;
}

// ---------------- K0: emb -> bf16 hi/lo split ----------------
__global__ void k_emb_cvt(const float* __restrict__ emb,
                          ushort* __restrict__ hi, ushort* __restrict__ lo) {
    int i = blockIdx.x * 256 + threadIdx.x;   // 65536 float4 groups
    float4 v = reinterpret_cast<const float4*>(emb)[i];
    ushort4 h, l;
    float x[4] = {v.x, v.y, v.z, v.w};
    ushort hb[4], lb[4];
    #pragma unroll
    for (int j = 0; j < 4; ++j) {
        unsigned hbits = bf16_rne_bits(x[j]);
        float hf = __uint_as_float(hbits << 16);
        unsigned lbits = bf16_rne_bits(x[j] - hf);
        hb[j] = (ushort)hbits; lb[j] = (ushort)lbits;
    }
    h.x = hb[0]; h.y = hb[1]; h.z = hb[2]; h.w = hb[3];
    l.x = lb[0]; l.y = lb[1]; l.z = lb[2]; l.w = lb[3];
    reinterpret_cast<ushort4*>(hi)[i] = h;
    reinterpret_cast<ushort4*>(lo)[i] = l;
}

// ---------------- K1: emb row norms (numpy-faithful) ----------------
__global__ void k_emb_norm(const float* __restrict__ emb, float* __restrict__ enorm) {
    int k = blockIdx.x * 256 + threadIdx.x;
    if (k < K_CODES) enorm[k] = pw_sum256_sq(emb + (size_t)k * D_DIM);
}

// ---------------- K2: MFMA screen (top-3 tracking) ----------------
#define BT_STR 264              // padded ushort stride (16B-aligned rows)
#define BT_BLK (16 * BT_STR)    // one 16-code half-tile (hi or lo)
__global__ __launch_bounds__(256, 2) void k_screen_mfma(
    const float* __restrict__ z,
    const ushort* __restrict__ emb_hi, const ushort* __restrict__ emb_lo,
    const float* __restrict__ enorm, float* __restrict__ zn_row,
    int* __restrict__ idx_ws, int* __restrict__ worklist,
    int* __restrict__ hardlist, int* __restrict__ nflag)
{
    __shared__ __align__(16) float zl[64 * 257];   // 65792 B; reused as B tiles
    __shared__ float enorm_lds[K_CODES];
    __shared__ float zn_sh[64];

    const int tid  = threadIdx.x;
    const int lane = tid & 63, wave = tid >> 6;
    const int blk  = blockIdx.x;                   // 512 blocks
    const int batch = blk >> 4;
    const int p0    = (blk & 15) * 64;
    const float* zb = z + (size_t)batch * D_DIM * HW;

    // stage z tile (f32): zl[p*257 + d] = z[batch][d][p0+p]
    {
        int p = tid & 63;
        for (int d = tid >> 6; d < D_DIM; d += 4)
            zl[p * 257 + d] = zb[(size_t)d * HW + p0 + p];
    }
    // stage enorm
    for (int i = tid; i < K_CODES; i += 256) enorm_lds[i] = enorm[i];
    __syncthreads();

    // numpy-faithful zn per row (also persisted for the recheck kernels)
    if (tid < 64) {
        float zn = pw_sum256_sq(&zl[tid * 257]);
        zn_sh[tid] = zn;
        zn_row[blk * 64 + tid] = zn;
    }

    // build A fragments in registers (hi/lo bf16), 16 rows per wave
    const int fr = lane & 15, fg = lane >> 4;
    bf16x8 Ah[8], Al[8];
    {
        const float* zr = &zl[(wave * 16 + fr) * 257];
        #pragma unroll
        for (int s = 0; s < 8; ++s) {
            int c0 = s * 32 + fg * 8;
            bf16x8 h, l;
            #pragma unroll
            for (int j = 0; j < 8; ++j) {
                float x = zr[c0 + j];
                unsigned hb = bf16_rne_bits(x);
                float hf = __uint_as_float(hb << 16);
                unsigned lb = bf16_rne_bits(x - hf);
                h[j] = (short)hb; l[j] = (short)lb;
            }
            Ah[s] = h; Al[s] = l;
        }
    }
    __syncthreads();   // zl (f32) dead; B tiles may now overwrite it

    ushort* bt = reinterpret_cast<ushort*>(zl);    // [2 buf][hi,lo][16][BT_STR]

    auto stage = [&](int buf, int kt) {
        int row = tid >> 5, d16 = tid & 31;
        #pragma unroll
        for (int i = 0; i < 2; ++i) {
            int r = row + 8 * i;
            size_t src = ((size_t)(kt * 16 + r) << 8) + d16 * 8;
            uint4 vh = *reinterpret_cast<const uint4*>(emb_hi + src);
            uint4 vl = *reinterpret_cast<const uint4*>(emb_lo + src);
            *reinterpret_cast<uint4*>(&bt[(buf * 2 + 0) * BT_BLK + r * BT_STR + d16 * 8]) = vh;
            *reinterpret_cast<uint4*>(&bt[(buf * 2 + 1) * BT_BLK + r * BT_STR + d16 * 8]) = vl;
        }
    };

    float zn4[4];
    #pragma unroll
    for (int r = 0; r < 4; ++r) zn4[r] = zn_sh[wave * 16 + fg * 4 + r];

    float b1v[4] = {1e30f, 1e30f, 1e30f, 1e30f};
    float b2v[4] = {1e30f, 1e30f, 1e30f, 1e30f};
    float b3v[4] = {1e30f, 1e30f, 1e30f, 1e30f};
    int   b1i[4] = {0, 0, 0, 0};
    int   b2i[4] = {0, 0, 0, 0};

    stage(0, 0);
    __syncthreads();

    const int boff = fr * BT_STR + fg * 8;
    for (int kt = 0; kt < 64; ++kt) {
        int cur = kt & 1;
        if (kt < 63) stage(cur ^ 1, kt + 1);

        f32x4 aHH = {0.f, 0.f, 0.f, 0.f};
        f32x4 aHM = {0.f, 0.f, 0.f, 0.f};
        f32x4 aLH = {0.f, 0.f, 0.f, 0.f};
        const ushort* bhp = bt + cur * 2 * BT_BLK + boff;
        const ushort* blp = bhp + BT_BLK;
        #pragma unroll
        for (int s = 0; s < 8; ++s) {
            bf16x8 Bh = *reinterpret_cast<const bf16x8*>(bhp + s * 32);
            bf16x8 Bl = *reinterpret_cast<const bf16x8*>(blp + s * 32);
            aHH = MFMA16(Ah[s], Bh, aHH);
            aHM = MFMA16(Ah[s], Bl, aHM);
            aLH = MFMA16(Al[s], Bh, aLH);
        }
        {
            #pragma clang fp contract(off)
            float en = enorm_lds[kt * 16 + fr];
            int kk = kt * 16 + fr;
            #pragma unroll
            for (int r = 0; r < 4; ++r) {
                float m  = aHH[r] + (aHM[r] + aLH[r]);
                float t1 = zn4[r] + en;
                float s  = t1 - 2.0f * m;
                if (s < b1v[r]) {
                    b3v[r] = b2v[r];
                    b2v[r] = b1v[r]; b2i[r] = b1i[r];
                    b1v[r] = s;      b1i[r] = kk;
                } else if (s < b2v[r]) {
                    b3v[r] = b2v[r];
                    b2v[r] = s;      b2i[r] = kk;
                } else if (s < b3v[r]) {
                    b3v[r] = s;
                }
            }
        }
        __syncthreads();
    }

    // top-3 merge across the 16 lanes of each row group
    const int n0w = blk * 64 + wave * 16;
    #pragma unroll
    for (int r = 0; r < 4; ++r) {
        float v1 = b1v[r]; int i1 = b1i[r];
        float v2 = b2v[r]; int i2 = b2i[r];
        float v3 = b3v[r];
        #pragma unroll
        for (int o = 8; o >= 1; o >>= 1) {
            float ov1 = __shfl_xor(v1, o); int oi1 = __shfl_xor(i1, o);
            float ov2 = __shfl_xor(v2, o); int oi2 = __shfl_xor(i2, o);
            float ov3 = __shfl_xor(v3, o);
            bool t1 = (ov1 < v1) || (ov1 == v1 && oi1 < i1);
            float w1  = t1 ? ov1 : v1;  int wi1 = t1 ? oi1 : i1;
            float l1  = t1 ? v1  : ov1; int li1 = t1 ? i1  : oi1;
            float wv2 = t1 ? ov2 : v2;  int wi2 = t1 ? oi2 : i2;
            float wv3 = t1 ? ov3 : v3;
            float lv2 = t1 ? v2  : ov2;
            bool t2 = (wv2 < l1) || (wv2 == l1 && wi2 < li1);
            float m2 = t2 ? wv2 : l1;   int mi2 = t2 ? wi2 : li1;
            float m3 = t2 ? fminf(wv3, l1) : fminf(wv2, lv2);
            v1 = w1; i1 = wi1; v2 = m2; i2 = mi2; v3 = m3;
        }
        if (fr == 0) {
            int n = n0w + fg * 4 + r;
            idx_ws[n] = i1;
            if (v3 - v1 <= TAU) {
                int slot = atomicAdd(&nflag[1], 1);    // hard: >=3 in band
                hardlist[slot] = n;
            } else if (v2 - v1 <= TAU) {
                int slot = atomicAdd(&nflag[0], 1);    // soft: exactly {i1,i2}
                worklist[slot] = n | (i2 << 16);
            }
        }
    }
}

// ---------------- K3: epilogue (zq, loss, idxf, enc ones, counts) ----------------
__global__ __launch_bounds__(256) void k_epilogue(
    const float* __restrict__ z, const float* __restrict__ emb,
    const int* __restrict__ idx_ws,
    float* __restrict__ zq_out, float* __restrict__ idxf_out,
    float* __restrict__ enc, float* __restrict__ loss_row,
    int* __restrict__ counts)
{
    __shared__ int kb[64];
    __shared__ float lpart[4][64];
    const int tid = threadIdx.x;
    const int blk = blockIdx.x;                 // 512
    const int batch = blk >> 4;
    const int p0 = (blk & 15) * 64;
    const int n0 = blk * 64;

    if (tid < 64) {
        int k = idx_ws[n0 + tid];
        kb[tid] = k;
        idxf_out[n0 + tid] = (float)k;
        enc[(size_t)(n0 + tid) * K_CODES + k] = 1.0f;
        atomicAdd(&counts[k], 1);
    }
    __syncthreads();

    int p = tid & 63, dg = tid >> 6;
    const float* zp = z + (size_t)batch * D_DIM * HW + p0 + p;
    float* zqp = zq_out + (size_t)batch * D_DIM * HW + p0 + p;
    const float* er = emb + (size_t)kb[p] * D_DIM;
    float ls = 0.0f;
    for (int d = dg * 64; d < dg * 64 + 64; ++d) {
        float e = er[d];
        float zv = zp[(size_t)d * HW];
        float df = e - zv;
        ls += df * df;
        zqp[(size_t)d * HW] = e;
    }
    lpart[dg][p] = ls;
    __syncthreads();
    if (tid < 64)
        loss_row[n0 + tid] = (lpart[0][tid] + lpart[1][tid]) + (lpart[2][tid] + lpart[3][tid]);
}

// ---------------- K4: pair recheck — one wave per soft-flagged row ----------------
// Exact f64 dots for the TWO band candidates only; lex-min on quantized (s,k)
// == np.argmin first-index semantics; repairs outputs only if winner changes.
__global__ __launch_bounds__(256) void k_pairfix(
    const float* __restrict__ z, const float* __restrict__ emb,
    const float* __restrict__ enorm, const float* __restrict__ zn_row,
    const int* __restrict__ worklist, const int* __restrict__ nflag,
    int* __restrict__ idx_ws, int* __restrict__ counts,
    float* __restrict__ loss_row, float* __restrict__ zq_out,
    float* __restrict__ idxf_out, float* __restrict__ enc)
{
    const int lane = threadIdx.x & 63;
    const int gw = blockIdx.x * 4 + (threadIdx.x >> 6);
    const int nw = gridDim.x * 4;
    const int nf = nflag[0];

    for (int j = gw; j < nf; j += nw) {
        const int e  = worklist[j];
        const int n  = e & 0xFFFF;
        const int i2 = e >> 16;
        const int i1 = idx_ws[n];
        const int batch = n >> 10, p = n & (HW - 1);
        const float* zp = z + (size_t)batch * D_DIM * HW + p;

        float zr[4], e1[4], e2[4];
        #pragma unroll
        for (int i = 0; i < 4; ++i) {
            int d = lane + 64 * i;
            zr[i] = zp[(size_t)d * HW];
            e1[i] = emb[(size_t)i1 * D_DIM + d];
            e2[i] = emb[(size_t)i2 * D_DIM + d];
        }
        double p1 = ((double)zr[0] * (double)e1[0] + (double)zr[1] * (double)e1[1])
                  + ((double)zr[2] * (double)e1[2] + (double)zr[3] * (double)e1[3]);
        double p2 = ((double)zr[0] * (double)e2[0] + (double)zr[1] * (double)e2[1])
                  + ((double)zr[2] * (double)e2[2] + (double)zr[3] * (double)e2[3]);
        #pragma unroll
        for (int o = 1; o <= 32; o <<= 1) {
            p1 += __shfl_xor(p1, o);
            p2 += __shfl_xor(p2, o);
        }
        float s1, s2;
        {
            #pragma clang fp contract(off)
            float zn = zn_row[n];
            float mf1 = (float)p1, mf2 = (float)p2;
            s1 = (zn + enorm[i1]) - 2.0f * mf1;
            s2 = (zn + enorm[i2]) - 2.0f * mf2;
        }
        const bool swap = (s2 < s1) || (s2 == s1 && i2 < i1);
        if (swap) {
            float lsum = 0.0f;
            float* zqp = zq_out + (size_t)batch * D_DIM * HW + p;
            #pragma unroll
            for (int i = 0; i < 4; ++i) {
                int d = lane + 64 * i;
                float df = e2[i] - zr[i];
                lsum += df * df;
                zqp[(size_t)d * HW] = e2[i];
            }
            #pragma unroll
            for (int o = 32; o >= 1; o >>= 1) lsum += __shfl_xor(lsum, o);
            if (lane == 0) {
                loss_row[n] = lsum;
                idx_ws[n] = i2;
                idxf_out[n] = (float)i2;
                enc[(size_t)n * K_CODES + i1] = 0.0f;
                enc[(size_t)n * K_CODES + i2] = 1.0f;
                atomicSub(&counts[i1], 1);
                atomicAdd(&counts[i2], 1);
            }
        }
    }
}

// ---------------- K5: hard recheck — full scan, one block per hard row (rare) ----------------
__global__ __launch_bounds__(256, 4) void k_hard(
    const float* __restrict__ z, const float* __restrict__ emb,
    const float* __restrict__ enorm, const float* __restrict__ zn_row,
    const int* __restrict__ hardlist, const int* __restrict__ nflag,
    int* __restrict__ idx_ws, int* __restrict__ counts,
    float* __restrict__ loss_row, float* __restrict__ zq_out,
    float* __restrict__ idxf_out, float* __restrict__ enc)
{
    __shared__ __align__(16) float zrow[D_DIM];
    __shared__ float wv[4]; __shared__ int wi[4];
    __shared__ int fi_sh;

    const int tid  = threadIdx.x;
    const int lane = tid & 63, wave = tid >> 6;
    const int slot = tid >> 2, qt = tid & 3;
    const int nf = nflag[1];

    for (int j = blockIdx.x; j < nf; j += gridDim.x) {
        const int n = hardlist[j];
        const int batch = n >> 10, p = n & (HW - 1);

        zrow[tid] = z[(size_t)batch * D_DIM * HW + (size_t)tid * HW + p];
        __syncthreads();

        float bv = 1e30f; int bi = 0;
        const float znr = zn_row[n];
        const float* zq4 = &zrow[qt * 64];

        for (int pp = 0; pp < 16; ++pp) {
            const int c = pp * 64 + slot;
            const float* er = emb + (size_t)c * D_DIM + qt * 64;
            double a0 = 0.0, a1 = 0.0, a2 = 0.0, a3 = 0.0;
            #pragma unroll
            for (int d = 0; d < 64; d += 4) {
                float4 e4 = *reinterpret_cast<const float4*>(er + d);
                float4 z4 = *reinterpret_cast<const float4*>(zq4 + d);
                a0 += (double)z4.x * (double)e4.x;
                a1 += (double)z4.y * (double)e4.y;
                a2 += (double)z4.z * (double)e4.z;
                a3 += (double)z4.w * (double)e4.w;
            }
            double part = (a0 + a1) + (a2 + a3);
            part += __shfl_xor(part, 1);   // fixed tree across qt
            part += __shfl_xor(part, 2);
            {
                #pragma clang fp contract(off)
                float mf = (float)part;
                float t1 = znr + enorm[c];
                float s  = t1 - 2.0f * mf;
                if (qt == 0) {
                    if (s < bv) { bv = s; bi = c; }   // c ascending per slot
                }
            }
        }
        if (qt != 0) bv = 1e30f;

        #pragma unroll
        for (int o = 32; o >= 1; o >>= 1) {
            float ov = __shfl_xor(bv, o);
            int   oi = __shfl_xor(bi, o);
            if (ov < bv || (ov == bv && oi < bi)) { bv = ov; bi = oi; }
        }
        if (lane == 0) { wv[wave] = bv; wi[wave] = bi; }
        __syncthreads();
        if (tid == 0) {
            float fv = wv[0]; int fi = wi[0];
            #pragma unroll
            for (int w = 1; w < 4; ++w)
                if (wv[w] < fv || (wv[w] == fv && wi[w] < fi)) { fv = wv[w]; fi = wi[w]; }
            fi_sh = fi;
        }
        __syncthreads();

        const int fi = fi_sh;
        const int old = idx_ws[n];
        if (fi != old && wave == 0) {
            float lsum = 0.0f;
            float* zqp = zq_out + (size_t)batch * D_DIM * HW + p;
            #pragma unroll
            for (int i = 0; i < 4; ++i) {
                int d = lane + 64 * i;
                float e = emb[(size_t)fi * D_DIM + d];
                float df = e - zrow[d];
                lsum += df * df;
                zqp[(size_t)d * HW] = e;
            }
            #pragma unroll
            for (int o = 32; o >= 1; o >>= 1) lsum += __shfl_xor(lsum, o);
            if (lane == 0) {
                loss_row[n] = lsum;
                idx_ws[n] = fi;
                idxf_out[n] = (float)fi;
                enc[(size_t)n * K_CODES + old] = 0.0f;
                enc[(size_t)n * K_CODES + fi] = 1.0f;
                atomicSub(&counts[old], 1);
                atomicAdd(&counts[fi], 1);
            }
        }
        __syncthreads();   // protect zrow before next row
    }
}

// ---------------- K6: finalize loss + perplexity ----------------
__global__ void k_final(const float* __restrict__ loss_row,
                        const int* __restrict__ counts,
                        float* __restrict__ out_loss, float* __restrict__ out_perp) {
    __shared__ float la[4], pa[4];
    int tid = threadIdx.x;
    float ls = 0.0f, ps = 0.0f;
    for (int i = tid; i < N_ROWS; i += 256) ls += loss_row[i];
    for (int i = tid; i < K_CODES; i += 256) {
        float em = (float)counts[i] * (1.0f / (float)N_ROWS);
        ps += em * logf(em + 1e-10f);
    }
    #pragma unroll
    for (int off = 32; off > 0; off >>= 1) {
        ls += __shfl_down(ls, off);
        ps += __shfl_down(ps, off);
    }
    if ((tid & 63) == 0) { la[tid >> 6] = ls; pa[tid >> 6] = ps; }
    __syncthreads();
    if (tid == 0) {
        float L = (la[0] + la[1] + la[2] + la[3]) * (1.25f / (float)((size_t)N_ROWS * D_DIM));
        float P = expf(-(pa[0] + pa[1] + pa[2] + pa[3]));
        *out_loss = L;
        *out_perp = P;
    }
}

extern "C" void kernel_launch(void* const* d_in, const int* in_sizes, int n_in,
                              void* d_out, int out_size, void* d_ws, size_t ws_size,
                              hipStream_t stream) {
    const float* z   = (const float*)d_in[0];
    const float* emb = (const float*)d_in[1];
    float* out = (float*)d_out;

    // output layout (floats): loss | z_q_out | perplexity | min_encodings | idx
    float* out_loss = out;
    float* out_zq   = out + 1;
    float* out_perp = out + 1 + (size_t)N_ROWS * D_DIM;
    float* out_enc  = out_perp + 1;
    float* out_idxf = out_enc + (size_t)N_ROWS * K_CODES;

    char* ws = (char*)d_ws;
    int*    idx_ws   = (int*)(ws + 0);           // 131072 B
    int*    counts   = (int*)(ws + 131072);      // 4096 B
    float*  enorm    = (float*)(ws + 135168);    // 4096 B
    float*  loss_row = (float*)(ws + 139264);    // 131072 B
    int*    worklist = (int*)(ws + 270336);      // 131072 B
    int*    nflag    = (int*)(ws + 401408);      // 256 B ([0]=soft, [1]=hard)
    ushort* emb_hi   = (ushort*)(ws + 401664);   // 524288 B
    ushort* emb_lo   = (ushort*)(ws + 925952);   // 524288 B
    float*  zn_row   = (float*)(ws + 1450240);   // 131072 B
    int*    hardlist = (int*)(ws + 1581312);     // 131072 B

    hipMemsetAsync(counts, 0, K_CODES * sizeof(int), stream);
    hipMemsetAsync(nflag, 0, 2 * sizeof(int), stream);
    hipMemsetAsync(out_enc, 0, (size_t)N_ROWS * K_CODES * sizeof(float), stream);

    k_emb_cvt<<<256, 256, 0, stream>>>(emb, emb_hi, emb_lo);
    k_emb_norm<<<(K_CODES + 255) / 256, 256, 0, stream>>>(emb, enorm);
    k_screen_mfma<<<512, 256, 0, stream>>>(z, emb_hi, emb_lo, enorm, zn_row,
                                           idx_ws, worklist, hardlist, nflag);
    k_epilogue<<<512, 256, 0, stream>>>(z, emb, idx_ws, out_zq, out_idxf,
                                        out_enc, loss_row, counts);
    k_pairfix<<<128, 256, 0, stream>>>(z, emb, enorm, zn_row, worklist, nflag,
                                       idx_ws, counts, loss_row, out_zq,
                                       out_idxf, out_enc);
    k_hard<<<64, 256, 0, stream>>>(z, emb, enorm, zn_row, hardlist, nflag,
                                   idx_ws, counts, loss_row, out_zq,
                                   out_idxf, out_enc);
    k_final<<<1, 256, 0, stream>>>(loss_row, counts, out_loss, out_perp);
}